// Round 4
// baseline (439.373 us; speedup 1.0000x reference)
//
#include <hip/hip_runtime.h>
#include <hip/hip_cooperative_groups.h>
#include <hip/hip_bf16.h>

namespace cg = cooperative_groups;

// Decoder loss, single cooperative kernel (R4).
// L=16384 candidates, N=10000 targets, K=8 (collapses to argmin; R1-proven).
// 256 blocks x 256 threads, all co-resident (1 wg/CU), grid.sync between phases.

#define NBLK 256
#define NTHR 256

struct Params {
  const float* pred; const float* cxyz; const float* crgb;
  const float* txyz; const float* trgb; const int* ktgt; const int* pnum;
  float4* klist; float4* ttile; float4* numden; float4* zcolor;
  unsigned long long* tmin; unsigned long long* fmin;
  int* keep; int* kidx; int* zerohit; int* elist;
  unsigned int* key; unsigned int* ghist; unsigned int* gbuf;
  float* thr_slot; int* counters; unsigned char* islm;
  float* out; int L; int N;
};

__global__ __launch_bounds__(NTHR, 1) void k_all(Params p) {
  cg::grid_group grid = cg::this_grid();
  __shared__ float4 tile[256];
  __shared__ unsigned int hist[256];
  __shared__ unsigned int buf[16384];   // 64 KB; block 0's radix workspace
  __shared__ unsigned int sB, sR;
  int tid = threadIdx.x, bid = blockIdx.x;
  int gidx = bid * NTHR + tid;
  int gsz = (int)gridDim.x * NTHR;
  int L = p.L, N = p.N;

  // ---------------- Phase 0: init everything ----------------
  for (int i = gidx; i < N; i += gsz) {
    float x = p.txyz[3*i], y = p.txyz[3*i+1], z = p.txyz[3*i+2];
    p.ttile[i] = make_float4(x, y, z, fmaf(x, x, fmaf(y, y, z * z)));
    p.tmin[i] = ~0ull;
  }
  for (int i = gidx; i < L; i += gsz) {
    p.numden[i] = make_float4(0.f, 0.f, 0.f, 0.f);
    p.zerohit[i] = 0;
    p.fmin[i] = ~0ull;
  }
  if (gidx < 2048) p.ghist[gidx] = 0u;
  if (gidx < 8) p.counters[gidx] = 0;
  if (gidx < 2) p.out[gidx] = 0.f;
  grid.sync();

  // ------- Phase 1: monotone keys + per-8 local max + 2048-bin hist -------
  int ngroups = L >> 3;
  for (int g = gidx; g < ngroups; g += gsz) {
    const float4* pv = (const float4*)p.pred + (size_t)g * 2;
    float4 a = pv[0], b = pv[1];
    float v[8] = {a.x, a.y, a.z, a.w, b.x, b.y, b.z, b.w};
    int bi = 0; float bv = v[0];
    #pragma unroll
    for (int j = 1; j < 8; ++j) if (v[j] > bv) { bv = v[j]; bi = j; }
    unsigned int kk[8];
    unsigned long long lmpack = 0ull;
    #pragma unroll
    for (int j = 0; j < 8; ++j) {
      unsigned int fb = __float_as_uint(v[j]);
      unsigned int mk = (fb & 0x80000000u) ? ~fb : (fb | 0x80000000u);
      if (j == bi) { mk = 0xFF800000u; lmpack |= 1ull << (8 * j); }  // +inf
      kk[j] = mk;
      atomicAdd(&p.ghist[mk >> 21], 1u);
    }
    ((uint4*)p.key)[g*2]   = make_uint4(kk[0], kk[1], kk[2], kk[3]);
    ((uint4*)p.key)[g*2+1] = make_uint4(kk[4], kk[5], kk[6], kk[7]);
    *(unsigned long long*)(p.islm + (size_t)g * 8) = lmpack;
  }
  grid.sync();

  // ------- Phase 2a: every block redundantly finds rank bin (B,R) -------
  unsigned int rank = (unsigned int)(L - p.pnum[0] - 1);
  if (tid < 64) {
    unsigned int sum = 0;
    for (int j = 0; j < 32; ++j) sum += p.ghist[tid * 32 + j];
    unsigned int incl = sum;
    for (int o = 1; o < 64; o <<= 1) {
      unsigned int vv = __shfl_up(incl, o);
      if (tid >= o) incl += vv;
    }
    unsigned int excl = incl - sum;
    bool cond = (rank >= excl) && (rank < incl);
    unsigned long long bal = __ballot(cond);
    int first = __ffsll((long long)bal) - 1;
    if (tid == first) {
      unsigned int r = rank - excl, cum = 0;
      for (int j = 0; j < 32; ++j) {
        unsigned int c = p.ghist[tid * 32 + j];
        if (r < cum + c) { sB = (unsigned int)(tid * 32 + j); sR = r - cum; break; }
        cum += c;
      }
    }
  }
  __syncthreads();
  unsigned int B = sB;
  // ------- Phase 2b: grid-parallel gather of bin-B keys -------
  for (int i = gidx; i < L; i += gsz) {
    unsigned int k = p.key[i];
    if ((k >> 21) == B) {
      unsigned int pos = atomicAdd((unsigned int*)&p.counters[2], 1u);
      p.gbuf[pos] = k;
    }
  }
  grid.sync();

  // ------- Phase 2c: block 0 in-LDS radix select -> exact threshold -------
  if (bid == 0) {
    unsigned int M = (unsigned int)p.counters[2];
    for (unsigned int j = tid; j < M; j += NTHR) buf[j] = p.gbuf[j];
    __syncthreads();
    unsigned int pfx = B << 21;
    const int shifts[3] = {13, 5, 0};
    const unsigned int masks[3] = {0xFFE00000u, 0xFFFFE000u, 0xFFFFFFE0u};
    const int nbs[3] = {256, 256, 32};
    for (int pass = 0; pass < 3; ++pass) {
      hist[tid] = 0u;
      __syncthreads();
      unsigned int mk = masks[pass]; int sh = shifts[pass]; int nb = nbs[pass];
      unsigned int pm = pfx & mk;
      for (unsigned int j = tid; j < M; j += NTHR) {
        unsigned int k = buf[j];
        if ((k & mk) == pm) atomicAdd(&hist[(k >> sh) & (unsigned)(nb - 1)], 1u);
      }
      __syncthreads();
      if (tid < 64) {
        int g = nb >> 6; if (g < 1) g = 1;
        unsigned int sum = 0;
        for (int j = 0; j < g; ++j) { int idx = tid * g + j; if (idx < nb) sum += hist[idx]; }
        unsigned int incl = sum;
        for (int o = 1; o < 64; o <<= 1) {
          unsigned int vv = __shfl_up(incl, o);
          if (tid >= o) incl += vv;
        }
        unsigned int excl = incl - sum;
        unsigned int r = sR;
        bool cond = (r >= excl) && (r < incl);
        unsigned long long bal = __ballot(cond);
        int first = __ffsll((long long)bal) - 1;
        if (tid == first) {
          unsigned int rr = r - excl, cum = 0;
          for (int j = 0; j < g; ++j) {
            int idx = tid * g + j; if (idx >= nb) break;
            unsigned int c = hist[idx];
            if (rr < cum + c) { sB = (unsigned int)idx; sR = rr - cum; break; }
            cum += c;
          }
        }
      }
      __syncthreads();
      pfx |= sB << sh;
      __syncthreads();
    }
    if (tid == 0) {
      unsigned int kk2 = pfx;
      unsigned int fb = (kk2 & 0x80000000u) ? (kk2 & 0x7FFFFFFFu) : ~kk2;
      p.thr_slot[0] = __uint_as_float(fb);
    }
  }
  grid.sync();

  // ------- Phase 3: keep mask + compaction + BCE reduce -------
  {
    float thr = p.thr_slot[0];
    float term = 0.f;
    for (int i = gidx; i < L; i += gsz) {
      float v = p.pred[i];
      bool kp = (v > thr) || p.islm[i];
      p.keep[i] = kp ? 1 : 0;
      if (kp) {
        int pos = atomicAdd(&p.counters[0], 1);  // order irrelevant (no ties)
        float x = p.cxyz[3*i], y = p.cxyz[3*i+1], z = p.cxyz[3*i+2];
        p.klist[pos] = make_float4(x, y, z, fmaf(x, x, fmaf(y, y, z * z)));
        p.kidx[pos] = i;
      }
      float t = (float)p.ktgt[i];
      term += fmaxf(v, 0.f) - v * t + log1pf(expf(-fabsf(v)));
    }
    for (int o = 32; o > 0; o >>= 1) term += __shfl_down(term, o);
    if ((tid & 63) == 0) atomicAdd(&p.out[0], term);
  }
  grid.sync();

  // ------- Phase 4: backward scan (target -> nearest kept candidate) -------
  {
    int kc = p.counters[0];
    int ntb = (N + 255) / 256;
    const int NC = 6;
    int csz = ((kc + NC - 1) / NC + 255) & ~255;
    for (int task = bid; task < ntb * NC; task += (int)gridDim.x) {
      int tb = task / NC, cb = task % NC;
      int c0 = cb * csz, c1 = min(c0 + csz, kc);
      int t = tb * 256 + tid;
      bool act = t < N;
      float tx = 0.f, ty = 0.f, tz = 0.f;
      if (act) { tx = p.txyz[3*t]; ty = p.txyz[3*t+1]; tz = p.txyz[3*t+2]; }
      float ntx = -2.f * tx, nty = -2.f * ty, ntz = -2.f * tz;
      float best = 3e38f; int bpos = -1;
      for (int tb0 = c0; tb0 < c1; tb0 += 256) {
        int cnt = min(256, c1 - tb0);
        __syncthreads();
        if (tid < cnt) tile[tid] = p.klist[tb0 + tid];
        __syncthreads();
        #pragma unroll 8
        for (int c = 0; c < cnt; ++c) {
          float4 cd = tile[c];
          // monotone surrogate |c|^2 - 2 t.c (argmin-equiv to |t-c|^2)
          float d = fmaf(ntx, cd.x, cd.w);
          d = fmaf(nty, cd.y, d);
          d = fmaf(ntz, cd.z, d);
          if (d < best) { best = d; bpos = tb0 + c; }
        }
      }
      if (act && bpos >= 0) {
        float4 cd = p.klist[bpos];
        float dx = tx - cd.x, dy = ty - cd.y, dz = tz - cd.z;
        float dtrue = fmaf(dx, dx, fmaf(dy, dy, dz * dz));  // exact (R1-proven)
        unsigned long long pack =
            ((unsigned long long)__float_as_uint(dtrue) << 32) |
            (unsigned int)p.kidx[bpos];
        atomicMin(&p.tmin[t], pack);
      }
    }
  }
  grid.sync();

  // ------- Phase 5: scatter weighted colors into num/den -------
  for (int t = gidx; t < N; t += gsz) {
    unsigned long long pack = p.tmin[t];
    float d = __uint_as_float((unsigned int)(pack >> 32));
    int idx = (int)(pack & 0xFFFFFFFFull);
    float r = p.trgb[3*t], g2 = p.trgb[3*t+1], b2 = p.trgb[3*t+2];
    if (d == 0.0f) {
      p.zerohit[idx] = 1;
      p.zcolor[idx] = make_float4(r, g2, b2, 0.f);
    } else {
      float w = 1.0f / sqrtf(fmaxf(d, 1e-30f));
      atomicAdd(&p.numden[idx].x, r * w);
      atomicAdd(&p.numden[idx].y, g2 * w);
      atomicAdd(&p.numden[idx].z, b2 * w);
      atomicAdd(&p.numden[idx].w, w);
    }
  }
  grid.sync();

  // ------- Phase 6: compact empty kept candidates -------
  for (int l = gidx; l < L; l += gsz) {
    if (p.keep[l] && (p.numden[l].w == 0.f) && (p.zerohit[l] == 0)) {
      int pos = atomicAdd(&p.counters[1], 1);
      p.elist[pos] = l;
    }
  }
  grid.sync();

  // ------- Phase 7: forward scan (empty kept candidate -> nearest target) ---
  {
    int ec = p.counters[1];
    int neb = (ec + 255) / 256;
    const int NTC = 5;
    int tcs = ((N + NTC - 1) / NTC + 255) & ~255;
    for (int task = bid; task < neb * NTC; task += (int)gridDim.x) {
      int eb = task / NTC, tc = task % NTC;
      int t0 = tc * tcs, t1 = min(t0 + tcs, N);
      int e = eb * 256 + tid;
      bool act = e < ec;
      int l = act ? p.elist[e] : 0;
      float cx = 0.f, cy = 0.f, cz = 0.f;
      if (act) { cx = p.cxyz[3*l]; cy = p.cxyz[3*l+1]; cz = p.cxyz[3*l+2]; }
      float ncx = -2.f * cx, ncy = -2.f * cy, ncz = -2.f * cz;
      float c2 = fmaf(cx, cx, fmaf(cy, cy, cz * cz));
      float best = 3e38f; int bx = 0;
      for (int tb0 = t0; tb0 < t1; tb0 += 256) {
        int cnt = min(256, t1 - tb0);
        __syncthreads();
        if (tid < cnt) tile[tid] = p.ttile[tb0 + tid];
        __syncthreads();
        #pragma unroll 8
        for (int c = 0; c < cnt; ++c) {
          float4 td = tile[c];
          float d = fmaf(ncx, td.x, td.w);
          d = fmaf(ncy, td.y, d);
          d = fmaf(ncz, td.z, d);
          if (d < best) { best = d; bx = tb0 + c; }
        }
      }
      if (act) {
        float dkey = fmaxf(best + c2, 0.f);  // consistent merge key
        unsigned long long pack =
            ((unsigned long long)__float_as_uint(dkey) << 32) | (unsigned int)bx;
        atomicMin(&p.fmin[l], pack);
      }
    }
  }
  grid.sync();

  // ------- Phase 8: final recolor select + L1 reduce -------
  {
    float loss = 0.f;
    for (int l = gidx; l < L; l += gsz) {
      if (p.keep[l]) {
        float rr, rg, rb;
        if (p.zerohit[l]) {
          float4 z = p.zcolor[l]; rr = z.x; rg = z.y; rb = z.z;
        } else {
          float4 nd = p.numden[l];
          if (nd.w != 0.f) { rr = nd.x / nd.w; rg = nd.y / nd.w; rb = nd.z / nd.w; }
          else {
            int ti = (int)(p.fmin[l] & 0xFFFFFFFFull);
            rr = p.trgb[3*ti]; rg = p.trgb[3*ti+1]; rb = p.trgb[3*ti+2];
          }
        }
        float sr = p.crgb[3*l]*255.f, sg = p.crgb[3*l+1]*255.f, sb = p.crgb[3*l+2]*255.f;
        loss += fabsf(sr - rr) + fabsf(sg - rg) + fabsf(sb - rb);
      }
    }
    for (int o = 32; o > 0; o >>= 1) loss += __shfl_down(loss, o);
    if ((tid & 63) == 0) atomicAdd(&p.out[1], loss);
  }
}

extern "C" void kernel_launch(void* const* d_in, const int* in_sizes, int n_in,
                              void* d_out, int out_size, void* d_ws, size_t ws_size,
                              hipStream_t stream) {
  Params prm;
  prm.pred = (const float*)d_in[0];
  prm.cxyz = (const float*)d_in[1];
  prm.crgb = (const float*)d_in[2];
  prm.txyz = (const float*)d_in[3];
  prm.trgb = (const float*)d_in[4];
  prm.ktgt = (const int*)d_in[5];
  prm.pnum = (const int*)d_in[6];
  int L = in_sizes[0];
  int N = in_sizes[3] / 3;
  prm.L = L; prm.N = N;

  // workspace layout: 16B arrays first, then 8B, then 4B, then bytes
  char* ws = (char*)d_ws;
  size_t off = 0;
  prm.klist  = (float4*)(ws + off);             off += (size_t)L * 16;
  prm.ttile  = (float4*)(ws + off);             off += (size_t)((N + 3) & ~3) * 16;
  prm.numden = (float4*)(ws + off);             off += (size_t)L * 16;
  prm.zcolor = (float4*)(ws + off);             off += (size_t)L * 16;
  prm.tmin   = (unsigned long long*)(ws + off); off += (size_t)((N + 1) & ~1) * 8;
  prm.fmin   = (unsigned long long*)(ws + off); off += (size_t)L * 8;
  prm.keep   = (int*)(ws + off);                off += (size_t)L * 4;
  prm.kidx   = (int*)(ws + off);                off += (size_t)L * 4;
  prm.zerohit= (int*)(ws + off);                off += (size_t)L * 4;
  prm.elist  = (int*)(ws + off);                off += (size_t)L * 4;
  prm.key    = (unsigned int*)(ws + off);       off += (size_t)L * 4;
  prm.gbuf   = (unsigned int*)(ws + off);       off += (size_t)L * 4;
  prm.ghist  = (unsigned int*)(ws + off);       off += 2048 * 4;
  prm.thr_slot = (float*)(ws + off);            off += 16;
  prm.counters = (int*)(ws + off);              off += 256;
  prm.islm   = (unsigned char*)(ws + off);      off += ((size_t)L + 15) & ~15ull;
  prm.out    = (float*)d_out;

  void* args[] = {&prm};
  hipLaunchCooperativeKernel((void*)k_all, dim3(NBLK), dim3(NTHR), args, 0, stream);
}

// Round 5
// 213.132 us; speedup vs baseline: 2.0615x; 2.0615x over previous
//
#include <hip/hip_runtime.h>
#include <hip/hip_bf16.h>

// Decoder loss: keep-mask (kth-value threshold + local max), BCE coord loss,
// bidirectional NN recolor + L1 rgb loss.
// L=16384 candidates, N=10000 targets, K=8 (collapses to argmin; R1-proven).
// R5: back to multi-kernel (R4 grid.sync cost ~40us each — never again).
//     8 kernels; self-contained k_sel (3-sweep LDS radix); LDS-free scans.

#define BCH 512      // kept-candidate chunk per blockIdx.y in k_bwd
#define FCH 512      // target chunk per blockIdx.y in k_fwd
typedef unsigned long long ull;

// ---- Kernel 1: init + monotone keys + per-8 local max (fused, race-free) ---
__global__ __launch_bounds__(256) void k_initprep(
    const float* __restrict__ pred, const float* __restrict__ txyz,
    float4* __restrict__ ttile, float4* __restrict__ numden,
    int* __restrict__ zerohit, ull* __restrict__ tmin, ull* __restrict__ fmin,
    unsigned int* __restrict__ key, unsigned char* __restrict__ islm,
    int* __restrict__ counters, float* __restrict__ out, int L, int N) {
  int gidx = blockIdx.x * 256 + threadIdx.x;
  int gsz = (int)gridDim.x * 256;
  for (int i = gidx; i < N; i += gsz) {
    float x = txyz[3*i], y = txyz[3*i+1], z = txyz[3*i+2];
    ttile[i] = make_float4(x, y, z, fmaf(x, x, fmaf(y, y, z * z)));
    tmin[i] = ~0ull;
  }
  for (int i = gidx; i < L; i += gsz) {
    numden[i] = make_float4(0.f, 0.f, 0.f, 0.f);
    zerohit[i] = 0;
    fmin[i] = ~0ull;
  }
  if (gidx < 8) counters[gidx] = 0;
  if (gidx < 2) out[gidx] = 0.f;
  int ngroups = L >> 3;
  for (int g = gidx; g < ngroups; g += gsz) {
    const float4* pv = (const float4*)pred + (size_t)g * 2;
    float4 a = pv[0], b = pv[1];
    float v[8] = {a.x, a.y, a.z, a.w, b.x, b.y, b.z, b.w};
    int bi = 0; float bv = v[0];
    #pragma unroll
    for (int j = 1; j < 8; ++j) if (v[j] > bv) { bv = v[j]; bi = j; }
    unsigned int kk[8];
    ull lmpack = 0ull;
    #pragma unroll
    for (int j = 0; j < 8; ++j) {
      unsigned int fb = __float_as_uint(v[j]);
      unsigned int mk = (fb & 0x80000000u) ? ~fb : (fb | 0x80000000u);
      if (j == bi) { mk = 0xFF800000u; lmpack |= 1ull << (8 * j); }  // +inf
      kk[j] = mk;
    }
    ((uint4*)key)[g*2]   = make_uint4(kk[0], kk[1], kk[2], kk[3]);
    ((uint4*)key)[g*2+1] = make_uint4(kk[4], kk[5], kk[6], kk[7]);
    *(ull*)(islm + (size_t)g * 8) = lmpack;
  }
}

// ---- helper: pick bin containing rank from LDS hist (wave 0), update sB/sR -
__device__ __forceinline__ void select_bin(
    unsigned int* hist, int nb, unsigned int rank,
    unsigned int* sB, unsigned int* sR, int tid) {
  if (tid < 64) {
    int g = nb >> 6;
    unsigned int sum = 0;
    for (int j = 0; j < g; ++j) sum += hist[tid * g + j];
    unsigned int incl = sum;
    for (int o = 1; o < 64; o <<= 1) {
      unsigned int v = __shfl_up(incl, o);
      if (tid >= o) incl += v;
    }
    unsigned int excl = incl - sum;
    bool cond = (rank >= excl) && (rank < incl);
    unsigned long long bal = __ballot(cond);
    int first = __ffsll((long long)bal) - 1;
    if (tid == first) {
      unsigned int r = rank - excl, cum = 0;
      for (int j = 0; j < g; ++j) {
        unsigned int c = hist[tid * g + j];
        if (r < cum + c) { *sB = (unsigned int)(tid * g + j); *sR = r - cum; break; }
        cum += c;
      }
    }
  }
}

// ---- Kernel 2: exact rank select, self-contained (1 block, 3 sweeps) -------
__global__ __launch_bounds__(256) void k_sel(
    const unsigned int* __restrict__ key, const int* __restrict__ pnum_p,
    float* __restrict__ thr_out, int L) {
  __shared__ unsigned int hist[2048];
  __shared__ unsigned int sB, sR;
  int tid = threadIdx.x;
  unsigned int rank = (unsigned int)(L - pnum_p[0] - 1);
  const uint4* k4 = (const uint4*)key;
  int n4 = L >> 2;
  // pass A: top 11 bits
  for (int b = tid; b < 2048; b += 256) hist[b] = 0u;
  __syncthreads();
  for (int i = tid; i < n4; i += 256) {
    uint4 v = k4[i];
    atomicAdd(&hist[v.x >> 21], 1u); atomicAdd(&hist[v.y >> 21], 1u);
    atomicAdd(&hist[v.z >> 21], 1u); atomicAdd(&hist[v.w >> 21], 1u);
  }
  __syncthreads();
  select_bin(hist, 2048, rank, &sB, &sR, tid);
  __syncthreads();
  unsigned int B1 = sB, R1 = sR;
  // pass B: bits [20:10]
  for (int b = tid; b < 2048; b += 256) hist[b] = 0u;
  __syncthreads();
  for (int i = tid; i < n4; i += 256) {
    uint4 v = k4[i];
    if ((v.x >> 21) == B1) atomicAdd(&hist[(v.x >> 10) & 2047u], 1u);
    if ((v.y >> 21) == B1) atomicAdd(&hist[(v.y >> 10) & 2047u], 1u);
    if ((v.z >> 21) == B1) atomicAdd(&hist[(v.z >> 10) & 2047u], 1u);
    if ((v.w >> 21) == B1) atomicAdd(&hist[(v.w >> 10) & 2047u], 1u);
  }
  __syncthreads();
  select_bin(hist, 2048, R1, &sB, &sR, tid);
  __syncthreads();
  unsigned int B2 = sB, R2 = sR;
  // pass C: bits [9:0]
  for (int b = tid; b < 1024; b += 256) hist[b] = 0u;
  __syncthreads();
  unsigned int top22 = (B1 << 11) | B2;
  for (int i = tid; i < n4; i += 256) {
    uint4 v = k4[i];
    if ((v.x >> 10) == top22) atomicAdd(&hist[v.x & 1023u], 1u);
    if ((v.y >> 10) == top22) atomicAdd(&hist[v.y & 1023u], 1u);
    if ((v.z >> 10) == top22) atomicAdd(&hist[v.z & 1023u], 1u);
    if ((v.w >> 10) == top22) atomicAdd(&hist[v.w & 1023u], 1u);
  }
  __syncthreads();
  select_bin(hist, 1024, R2, &sB, &sR, tid);
  __syncthreads();
  if (tid == 0) {
    unsigned int fkey = (B1 << 21) | (B2 << 10) | sB;
    unsigned int fb = (fkey & 0x80000000u) ? (fkey & 0x7FFFFFFFu) : ~fkey;
    thr_out[0] = __uint_as_float(fb);
  }
}

// ---- Kernel 3: keep mask + compaction + BCE reduce -------------------------
__global__ __launch_bounds__(256) void k_keepc(
    const float* __restrict__ pred, const unsigned char* __restrict__ islm,
    const float* __restrict__ thr_p, const float* __restrict__ cxyz,
    const int* __restrict__ ktgt, int* __restrict__ keep,
    float4* __restrict__ klist, int* __restrict__ kidx,
    int* __restrict__ counters, float* __restrict__ out, int L) {
  int i = blockIdx.x * 256 + threadIdx.x;
  float thr = thr_p[0];
  float term = 0.f;
  if (i < L) {
    float p = pred[i];
    bool kp = (p > thr) || islm[i];
    keep[i] = kp ? 1 : 0;
    if (kp) {
      int pos = atomicAdd(&counters[0], 1);   // order irrelevant (no ties)
      float x = cxyz[3*i], y = cxyz[3*i+1], z = cxyz[3*i+2];
      klist[pos] = make_float4(x, y, z, fmaf(x, x, fmaf(y, y, z * z)));
      kidx[pos] = i;
    }
    float t = (float)ktgt[i];
    term = fmaxf(p, 0.f) - p * t + log1pf(expf(-fabsf(p)));
  }
  for (int o = 32; o > 0; o >>= 1) term += __shfl_down(term, o);
  if ((threadIdx.x & 63) == 0) atomicAdd(&out[0], term);
}

// ---- Kernel 4: backward argmin (wave-uniform candidate stream, no LDS) -----
__global__ __launch_bounds__(256) void k_bwd(
    const float* __restrict__ txyz, const float4* __restrict__ klist,
    const int* __restrict__ kidx, const int* __restrict__ counters,
    ull* __restrict__ tmin, int N) {
  int kc = counters[0];
  int c0 = blockIdx.y * BCH;
  if (c0 >= kc) return;                 // uniform early-exit
  int c1 = min(c0 + BCH, kc);
  int t = blockIdx.x * 256 + threadIdx.x;
  bool act = t < N;
  float tx = 0.f, ty = 0.f, tz = 0.f;
  if (act) { tx = txyz[3*t]; ty = txyz[3*t+1]; tz = txyz[3*t+2]; }
  float ntx = -2.f * tx, nty = -2.f * ty, ntz = -2.f * tz;
  float b0 = 3e38f, b1 = 3e38f; int p0 = -1, p1 = -1;
  int c = c0;
  for (; c + 2 <= c1; c += 2) {
    float4 A = klist[c], B = klist[c + 1];
    // monotone surrogate |c|^2 - 2 t.c (argmin-equiv to |t-c|^2)
    float dA = fmaf(ntx, A.x, A.w); dA = fmaf(nty, A.y, dA); dA = fmaf(ntz, A.z, dA);
    float dB = fmaf(ntx, B.x, B.w); dB = fmaf(nty, B.y, dB); dB = fmaf(ntz, B.z, dB);
    if (dA < b0) { b0 = dA; p0 = c; }
    if (dB < b1) { b1 = dB; p1 = c + 1; }
  }
  if (c < c1) {
    float4 A = klist[c];
    float dA = fmaf(ntx, A.x, A.w); dA = fmaf(nty, A.y, dA); dA = fmaf(ntz, A.z, dA);
    if (dA < b0) { b0 = dA; p0 = c; }
  }
  if (b1 < b0) { b0 = b1; p0 = p1; }
  if (act && p0 >= 0) {
    float4 cd = klist[p0];
    float dx = tx - cd.x, dy = ty - cd.y, dz = tz - cd.z;
    float dtrue = fmaf(dx, dx, fmaf(dy, dy, dz * dz));  // exact (R1-proven)
    ull pack = ((ull)__float_as_uint(dtrue) << 32) | (unsigned int)kidx[p0];
    atomicMin(&tmin[t], pack);
  }
}

// ---- Kernel 5: scatter weighted colors into num/den ------------------------
__global__ __launch_bounds__(256) void k_scatter(
    const float* __restrict__ trgb, const ull* __restrict__ tmin,
    float4* __restrict__ numden, int* __restrict__ zerohit,
    float4* __restrict__ zcolor, int N) {
  int t = blockIdx.x * 256 + threadIdx.x;
  if (t >= N) return;
  ull pack = tmin[t];
  float d = __uint_as_float((unsigned int)(pack >> 32));
  int idx = (int)(pack & 0xFFFFFFFFull);
  float r = trgb[3*t], g = trgb[3*t+1], b = trgb[3*t+2];
  if (d == 0.0f) {
    zerohit[idx] = 1;
    zcolor[idx] = make_float4(r, g, b, 0.f);
  } else {
    float w = 1.0f / sqrtf(fmaxf(d, 1e-30f));
    atomicAdd(&numden[idx].x, r * w);
    atomicAdd(&numden[idx].y, g * w);
    atomicAdd(&numden[idx].z, b * w);
    atomicAdd(&numden[idx].w, w);
  }
}

// ---- Kernel 6: compact empty kept candidates -------------------------------
__global__ __launch_bounds__(256) void k_empty(
    const int* __restrict__ keep, const float4* __restrict__ numden,
    const int* __restrict__ zerohit, int* __restrict__ elist,
    int* __restrict__ counters, int L) {
  int l = blockIdx.x * 256 + threadIdx.x;
  if (l < L && keep[l] && (numden[l].w == 0.f) && (zerohit[l] == 0)) {
    int pos = atomicAdd(&counters[1], 1);
    elist[pos] = l;
  }
}

// ---- Kernel 7: forward argmin (empties only; uniform target stream) --------
__global__ __launch_bounds__(256) void k_fwd(
    const float4* __restrict__ ttile, const float* __restrict__ cxyz,
    const int* __restrict__ elist, const int* __restrict__ counters,
    ull* __restrict__ fmin, int N) {
  int ec = counters[1];
  if ((int)(blockIdx.x * 256) >= ec) return;   // uniform early-exit
  int t0 = blockIdx.y * FCH;
  int t1 = min(t0 + FCH, N);
  int e = blockIdx.x * 256 + threadIdx.x;
  bool act = e < ec;
  int l = act ? elist[e] : 0;
  float cx = 0.f, cy = 0.f, cz = 0.f;
  if (act) { cx = cxyz[3*l]; cy = cxyz[3*l+1]; cz = cxyz[3*l+2]; }
  float ncx = -2.f * cx, ncy = -2.f * cy, ncz = -2.f * cz;
  float c2 = fmaf(cx, cx, fmaf(cy, cy, cz * cz));
  float b0 = 3e38f, b1 = 3e38f; int p0 = 0, p1 = 0;
  int c = t0;
  for (; c + 2 <= t1; c += 2) {
    float4 A = ttile[c], B = ttile[c + 1];
    float dA = fmaf(ncx, A.x, A.w); dA = fmaf(ncy, A.y, dA); dA = fmaf(ncz, A.z, dA);
    float dB = fmaf(ncx, B.x, B.w); dB = fmaf(ncy, B.y, dB); dB = fmaf(ncz, B.z, dB);
    if (dA < b0) { b0 = dA; p0 = c; }
    if (dB < b1) { b1 = dB; p1 = c + 1; }
  }
  if (c < t1) {
    float4 A = ttile[c];
    float dA = fmaf(ncx, A.x, A.w); dA = fmaf(ncy, A.y, dA); dA = fmaf(ncz, A.z, dA);
    if (dA < b0) { b0 = dA; p0 = c; }
  }
  if (b1 < b0) { b0 = b1; p0 = p1; }
  if (act) {
    float dkey = fmaxf(b0 + c2, 0.f);   // consistent merge key across chunks
    ull pack = ((ull)__float_as_uint(dkey) << 32) | (unsigned int)p0;
    atomicMin(&fmin[l], pack);
  }
}

// ---- Kernel 8: final recolor select + L1 reduce ----------------------------
__global__ __launch_bounds__(256) void k_loss(
    const float* __restrict__ crgb, const float* __restrict__ trgb,
    const int* __restrict__ keep, const float4* __restrict__ numden,
    const int* __restrict__ zerohit, const float4* __restrict__ zcolor,
    const ull* __restrict__ fmin, float* __restrict__ out, int L) {
  int l = blockIdx.x * 256 + threadIdx.x;
  float loss = 0.f;
  if (l < L && keep[l]) {
    float rr, rg, rb;
    if (zerohit[l]) {
      float4 z = zcolor[l]; rr = z.x; rg = z.y; rb = z.z;
    } else {
      float4 nd = numden[l];
      if (nd.w != 0.f) { rr = nd.x / nd.w; rg = nd.y / nd.w; rb = nd.z / nd.w; }
      else {
        int ti = (int)(fmin[l] & 0xFFFFFFFFull);
        rr = trgb[3*ti]; rg = trgb[3*ti+1]; rb = trgb[3*ti+2];
      }
    }
    float sr = crgb[3*l]*255.f, sg = crgb[3*l+1]*255.f, sb = crgb[3*l+2]*255.f;
    loss = fabsf(sr - rr) + fabsf(sg - rg) + fabsf(sb - rb);
  }
  for (int o = 32; o > 0; o >>= 1) loss += __shfl_down(loss, o);
  if ((threadIdx.x & 63) == 0) atomicAdd(&out[1], loss);
}

extern "C" void kernel_launch(void* const* d_in, const int* in_sizes, int n_in,
                              void* d_out, int out_size, void* d_ws, size_t ws_size,
                              hipStream_t stream) {
  const float* pred = (const float*)d_in[0];
  const float* cxyz = (const float*)d_in[1];
  const float* crgb = (const float*)d_in[2];
  const float* txyz = (const float*)d_in[3];
  const float* trgb = (const float*)d_in[4];
  const int*   ktgt = (const int*)d_in[5];
  const int*   pnum = (const int*)d_in[6];
  int L = in_sizes[0];
  int N = in_sizes[3] / 3;

  // workspace layout: 16B arrays first, then 8B, 4B, bytes
  char* ws = (char*)d_ws;
  size_t off = 0;
  float4* klist  = (float4*)(ws + off);   off += (size_t)L * 16;
  float4* ttile  = (float4*)(ws + off);   off += (size_t)((N + 3) & ~3) * 16;
  float4* numden = (float4*)(ws + off);   off += (size_t)L * 16;
  float4* zcolor = (float4*)(ws + off);   off += (size_t)L * 16;
  unsigned int* key = (unsigned int*)(ws + off); off += (size_t)L * 4;  // 16B-aligned (uint4)
  ull* tmin      = (ull*)(ws + off);      off += (size_t)((N + 1) & ~1) * 8;
  ull* fmin      = (ull*)(ws + off);      off += (size_t)L * 8;
  int* keep      = (int*)(ws + off);      off += (size_t)L * 4;
  int* kidx      = (int*)(ws + off);      off += (size_t)L * 4;
  int* zerohit   = (int*)(ws + off);      off += (size_t)L * 4;
  int* elist     = (int*)(ws + off);      off += (size_t)L * 4;
  float* thr_slot = (float*)(ws + off);   off += 16;
  int* counters  = (int*)(ws + off);      off += 256;   // [0]=kcount [1]=ecount
  unsigned char* islm = (unsigned char*)(ws + off); off += ((size_t)L + 15) & ~15ull;
  float* out = (float*)d_out;

  int nbL = (L + 255) / 256;   // 64
  int nbN = (N + 255) / 256;   // 40
  int mx = max(L, N);

  k_initprep<<<(mx + 255) / 256, 256, 0, stream>>>(
      pred, txyz, ttile, numden, zerohit, tmin, fmin, key, islm, counters, out, L, N);

  k_sel<<<1, 256, 0, stream>>>(key, pnum, thr_slot, L);

  k_keepc<<<nbL, 256, 0, stream>>>(
      pred, islm, thr_slot, cxyz, ktgt, keep, klist, kidx, counters, out, L);

  dim3 g2(nbN, (L + BCH - 1) / BCH);
  k_bwd<<<g2, 256, 0, stream>>>(txyz, klist, kidx, counters, tmin, N);

  k_scatter<<<nbN, 256, 0, stream>>>(trgb, tmin, numden, zerohit, zcolor, N);

  k_empty<<<nbL, 256, 0, stream>>>(keep, numden, zerohit, elist, counters, L);

  dim3 g3(nbL, (N + FCH - 1) / FCH);
  k_fwd<<<g3, 256, 0, stream>>>(ttile, cxyz, elist, counters, fmin, N);

  k_loss<<<nbL, 256, 0, stream>>>(
      crgb, trgb, keep, numden, zerohit, zcolor, fmin, out, L);
}

// Round 6
// 154.827 us; speedup vs baseline: 2.8378x; 1.3766x over previous
//
#include <hip/hip_runtime.h>
#include <hip/hip_bf16.h>

// Decoder loss: keep-mask (kth-value threshold + local max), BCE coord loss,
// bidirectional NN recolor + L1 rgb loss.
// L=16384 candidates, N=10000 targets, K=8 (collapses to argmin; R1-proven).
// R6: R3's LDS-tiled scans (R5's uniform global streaming was latency-bound:
//     k_fwd 55us @ 7% VALU) + R5's fused init and self-contained k_sel.
//     Never grid.sync on this part (R4: ~40us each).

#define SCAN_T 256   // threads per scan block
#define BCH 512      // kept-candidate chunk per blockIdx.y in k_bwd
#define FCH 512      // target chunk per blockIdx.y in k_fwd
typedef unsigned long long ull;

// ---- Kernel 1: init + monotone keys + per-8 local max (fused, race-free) ---
__global__ __launch_bounds__(256) void k_initprep(
    const float* __restrict__ pred, const float* __restrict__ txyz,
    float4* __restrict__ ttile, float4* __restrict__ numden,
    int* __restrict__ zerohit, ull* __restrict__ tmin, ull* __restrict__ fmin,
    unsigned int* __restrict__ key, unsigned char* __restrict__ islm,
    int* __restrict__ counters, float* __restrict__ out, int L, int N) {
  int gidx = blockIdx.x * 256 + threadIdx.x;
  int gsz = (int)gridDim.x * 256;
  for (int i = gidx; i < N; i += gsz) {
    float x = txyz[3*i], y = txyz[3*i+1], z = txyz[3*i+2];
    ttile[i] = make_float4(x, y, z, fmaf(x, x, fmaf(y, y, z * z)));
    tmin[i] = ~0ull;
  }
  for (int i = gidx; i < L; i += gsz) {
    numden[i] = make_float4(0.f, 0.f, 0.f, 0.f);
    zerohit[i] = 0;
    fmin[i] = ~0ull;
  }
  if (gidx < 8) counters[gidx] = 0;
  if (gidx < 2) out[gidx] = 0.f;
  int ngroups = L >> 3;
  for (int g = gidx; g < ngroups; g += gsz) {
    const float4* pv = (const float4*)pred + (size_t)g * 2;
    float4 a = pv[0], b = pv[1];
    float v[8] = {a.x, a.y, a.z, a.w, b.x, b.y, b.z, b.w};
    int bi = 0; float bv = v[0];
    #pragma unroll
    for (int j = 1; j < 8; ++j) if (v[j] > bv) { bv = v[j]; bi = j; }
    unsigned int kk[8];
    ull lmpack = 0ull;
    #pragma unroll
    for (int j = 0; j < 8; ++j) {
      unsigned int fb = __float_as_uint(v[j]);
      unsigned int mk = (fb & 0x80000000u) ? ~fb : (fb | 0x80000000u);
      if (j == bi) { mk = 0xFF800000u; lmpack |= 1ull << (8 * j); }  // +inf
      kk[j] = mk;
    }
    ((uint4*)key)[g*2]   = make_uint4(kk[0], kk[1], kk[2], kk[3]);
    ((uint4*)key)[g*2+1] = make_uint4(kk[4], kk[5], kk[6], kk[7]);
    *(ull*)(islm + (size_t)g * 8) = lmpack;
  }
}

// ---- helper: pick bin containing rank from LDS hist (wave 0), update sB/sR -
__device__ __forceinline__ void select_bin(
    unsigned int* hist, int nb, unsigned int rank,
    unsigned int* sB, unsigned int* sR, int tid) {
  if (tid < 64) {
    int g = nb >> 6;
    unsigned int sum = 0;
    for (int j = 0; j < g; ++j) sum += hist[tid * g + j];
    unsigned int incl = sum;
    for (int o = 1; o < 64; o <<= 1) {
      unsigned int v = __shfl_up(incl, o);
      if (tid >= o) incl += v;
    }
    unsigned int excl = incl - sum;
    bool cond = (rank >= excl) && (rank < incl);
    unsigned long long bal = __ballot(cond);
    int first = __ffsll((long long)bal) - 1;
    if (tid == first) {
      unsigned int r = rank - excl, cum = 0;
      for (int j = 0; j < g; ++j) {
        unsigned int c = hist[tid * g + j];
        if (r < cum + c) { *sB = (unsigned int)(tid * g + j); *sR = r - cum; break; }
        cum += c;
      }
    }
  }
}

// ---- Kernel 2: exact rank select, self-contained (1 block, 3 sweeps) -------
__global__ __launch_bounds__(256) void k_sel(
    const unsigned int* __restrict__ key, const int* __restrict__ pnum_p,
    float* __restrict__ thr_out, int L) {
  __shared__ unsigned int hist[2048];
  __shared__ unsigned int sB, sR;
  int tid = threadIdx.x;
  unsigned int rank = (unsigned int)(L - pnum_p[0] - 1);
  const uint4* k4 = (const uint4*)key;
  int n4 = L >> 2;
  // pass A: top 11 bits
  for (int b = tid; b < 2048; b += 256) hist[b] = 0u;
  __syncthreads();
  for (int i = tid; i < n4; i += 256) {
    uint4 v = k4[i];
    atomicAdd(&hist[v.x >> 21], 1u); atomicAdd(&hist[v.y >> 21], 1u);
    atomicAdd(&hist[v.z >> 21], 1u); atomicAdd(&hist[v.w >> 21], 1u);
  }
  __syncthreads();
  select_bin(hist, 2048, rank, &sB, &sR, tid);
  __syncthreads();
  unsigned int B1 = sB, R1 = sR;
  // pass B: bits [20:10]
  for (int b = tid; b < 2048; b += 256) hist[b] = 0u;
  __syncthreads();
  for (int i = tid; i < n4; i += 256) {
    uint4 v = k4[i];
    if ((v.x >> 21) == B1) atomicAdd(&hist[(v.x >> 10) & 2047u], 1u);
    if ((v.y >> 21) == B1) atomicAdd(&hist[(v.y >> 10) & 2047u], 1u);
    if ((v.z >> 21) == B1) atomicAdd(&hist[(v.z >> 10) & 2047u], 1u);
    if ((v.w >> 21) == B1) atomicAdd(&hist[(v.w >> 10) & 2047u], 1u);
  }
  __syncthreads();
  select_bin(hist, 2048, R1, &sB, &sR, tid);
  __syncthreads();
  unsigned int B2 = sB, R2 = sR;
  // pass C: bits [9:0]
  for (int b = tid; b < 1024; b += 256) hist[b] = 0u;
  __syncthreads();
  unsigned int top22 = (B1 << 11) | B2;
  for (int i = tid; i < n4; i += 256) {
    uint4 v = k4[i];
    if ((v.x >> 10) == top22) atomicAdd(&hist[v.x & 1023u], 1u);
    if ((v.y >> 10) == top22) atomicAdd(&hist[v.y & 1023u], 1u);
    if ((v.z >> 10) == top22) atomicAdd(&hist[v.z & 1023u], 1u);
    if ((v.w >> 10) == top22) atomicAdd(&hist[v.w & 1023u], 1u);
  }
  __syncthreads();
  select_bin(hist, 1024, R2, &sB, &sR, tid);
  __syncthreads();
  if (tid == 0) {
    unsigned int fkey = (B1 << 21) | (B2 << 10) | sB;
    unsigned int fb = (fkey & 0x80000000u) ? (fkey & 0x7FFFFFFFu) : ~fkey;
    thr_out[0] = __uint_as_float(fb);
  }
}

// ---- Kernel 3: keep mask + compaction + BCE reduce -------------------------
__global__ __launch_bounds__(256) void k_keepc(
    const float* __restrict__ pred, const unsigned char* __restrict__ islm,
    const float* __restrict__ thr_p, const float* __restrict__ cxyz,
    const int* __restrict__ ktgt, int* __restrict__ keep,
    float4* __restrict__ klist, int* __restrict__ kidx,
    int* __restrict__ counters, float* __restrict__ out, int L) {
  int i = blockIdx.x * 256 + threadIdx.x;
  float thr = thr_p[0];
  float term = 0.f;
  if (i < L) {
    float p = pred[i];
    bool kp = (p > thr) || islm[i];
    keep[i] = kp ? 1 : 0;
    if (kp) {
      int pos = atomicAdd(&counters[0], 1);   // order irrelevant (no ties)
      float x = cxyz[3*i], y = cxyz[3*i+1], z = cxyz[3*i+2];
      klist[pos] = make_float4(x, y, z, fmaf(x, x, fmaf(y, y, z * z)));
      kidx[pos] = i;
    }
    float t = (float)ktgt[i];
    term = fmaxf(p, 0.f) - p * t + log1pf(expf(-fabsf(p)));
  }
  for (int o = 32; o > 0; o >>= 1) term += __shfl_down(term, o);
  if ((threadIdx.x & 63) == 0) atomicAdd(&out[0], term);
}

// ---- Kernel 4: backward argmin, LDS-tiled (R3-proven) ----------------------
__global__ __launch_bounds__(SCAN_T) void k_bwd(
    const float* __restrict__ txyz, const float4* __restrict__ klist,
    const int* __restrict__ kidx, const int* __restrict__ counters,
    ull* __restrict__ tmin, int N) {
  int kc = counters[0];
  int c0 = blockIdx.y * BCH;
  if (c0 >= kc) return;                 // uniform early-exit
  int c1 = min(c0 + BCH, kc);
  __shared__ float4 sc[SCAN_T];
  int tid = threadIdx.x;
  int t = blockIdx.x * SCAN_T + tid;
  float tx = 0.f, ty = 0.f, tz = 0.f;
  if (t < N) { tx = txyz[3*t]; ty = txyz[3*t+1]; tz = txyz[3*t+2]; }
  float ntx = -2.f * tx, nty = -2.f * ty, ntz = -2.f * tz;
  float best = 3e38f; int bpos = -1;
  for (int tile = c0; tile < c1; tile += SCAN_T) {
    int cnt = min(SCAN_T, c1 - tile);
    if (tid < cnt) sc[tid] = klist[tile + tid];
    __syncthreads();
    #pragma unroll 8
    for (int c = 0; c < cnt; ++c) {
      float4 cd = sc[c];
      // monotone surrogate |c|^2 - 2 t.c (argmin-equiv to |t-c|^2)
      float d = fmaf(ntx, cd.x, cd.w);
      d = fmaf(nty, cd.y, d);
      d = fmaf(ntz, cd.z, d);
      if (d < best) { best = d; bpos = tile + c; }
    }
    __syncthreads();
  }
  if (t < N && bpos >= 0) {
    float4 cd = klist[bpos];
    float dx = tx - cd.x, dy = ty - cd.y, dz = tz - cd.z;
    float dtrue = fmaf(dx, dx, fmaf(dy, dy, dz * dz));  // exact (R1-proven)
    ull pack = ((ull)__float_as_uint(dtrue) << 32) | (unsigned int)kidx[bpos];
    atomicMin(&tmin[t], pack);
  }
}

// ---- Kernel 5: scatter weighted colors into num/den ------------------------
__global__ __launch_bounds__(256) void k_scatter(
    const float* __restrict__ trgb, const ull* __restrict__ tmin,
    float4* __restrict__ numden, int* __restrict__ zerohit,
    float4* __restrict__ zcolor, int N) {
  int t = blockIdx.x * 256 + threadIdx.x;
  if (t >= N) return;
  ull pack = tmin[t];
  float d = __uint_as_float((unsigned int)(pack >> 32));
  int idx = (int)(pack & 0xFFFFFFFFull);
  float r = trgb[3*t], g = trgb[3*t+1], b = trgb[3*t+2];
  if (d == 0.0f) {
    zerohit[idx] = 1;
    zcolor[idx] = make_float4(r, g, b, 0.f);
  } else {
    float w = 1.0f / sqrtf(fmaxf(d, 1e-30f));
    atomicAdd(&numden[idx].x, r * w);
    atomicAdd(&numden[idx].y, g * w);
    atomicAdd(&numden[idx].z, b * w);
    atomicAdd(&numden[idx].w, w);
  }
}

// ---- Kernel 6: compact empty kept candidates -------------------------------
__global__ __launch_bounds__(256) void k_empty(
    const int* __restrict__ keep, const float4* __restrict__ numden,
    const int* __restrict__ zerohit, int* __restrict__ elist,
    int* __restrict__ counters, int L) {
  int l = blockIdx.x * 256 + threadIdx.x;
  if (l < L && keep[l] && (numden[l].w == 0.f) && (zerohit[l] == 0)) {
    int pos = atomicAdd(&counters[1], 1);
    elist[pos] = l;
  }
}

// ---- Kernel 7: forward argmin (empties only), LDS-tiled (R3-proven) --------
__global__ __launch_bounds__(SCAN_T) void k_fwd(
    const float4* __restrict__ ttile, const float* __restrict__ cxyz,
    const int* __restrict__ elist, const int* __restrict__ counters,
    ull* __restrict__ fmin, int N) {
  int ec = counters[1];
  if ((int)(blockIdx.x * SCAN_T) >= ec) return;   // uniform early-exit
  __shared__ float4 st[SCAN_T];
  int tid = threadIdx.x;
  int e = blockIdx.x * SCAN_T + tid;
  bool act = e < ec;
  int l = act ? elist[e] : 0;
  float cx = 0.f, cy = 0.f, cz = 0.f;
  if (act) { cx = cxyz[3*l]; cy = cxyz[3*l+1]; cz = cxyz[3*l+2]; }
  float ncx = -2.f * cx, ncy = -2.f * cy, ncz = -2.f * cz;
  float c2 = fmaf(cx, cx, fmaf(cy, cy, cz * cz));
  int t0 = blockIdx.y * FCH;
  int t1 = min(t0 + FCH, N);
  float best = 3e38f; int bidx = 0;
  for (int tile = t0; tile < t1; tile += SCAN_T) {
    int cnt = min(SCAN_T, t1 - tile);
    if (tid < cnt) st[tid] = ttile[tile + tid];
    __syncthreads();
    #pragma unroll 8
    for (int c = 0; c < cnt; ++c) {
      float4 td = st[c];
      float d = fmaf(ncx, td.x, td.w);
      d = fmaf(ncy, td.y, d);
      d = fmaf(ncz, td.z, d);
      if (d < best) { best = d; bidx = tile + c; }
    }
    __syncthreads();
  }
  if (act) {
    float dkey = fmaxf(best + c2, 0.f);   // consistent merge key across chunks
    ull pack = ((ull)__float_as_uint(dkey) << 32) | (unsigned int)bidx;
    atomicMin(&fmin[l], pack);
  }
}

// ---- Kernel 8: final recolor select + L1 reduce ----------------------------
__global__ __launch_bounds__(256) void k_loss(
    const float* __restrict__ crgb, const float* __restrict__ trgb,
    const int* __restrict__ keep, const float4* __restrict__ numden,
    const int* __restrict__ zerohit, const float4* __restrict__ zcolor,
    const ull* __restrict__ fmin, float* __restrict__ out, int L) {
  int l = blockIdx.x * 256 + threadIdx.x;
  float loss = 0.f;
  if (l < L && keep[l]) {
    float rr, rg, rb;
    if (zerohit[l]) {
      float4 z = zcolor[l]; rr = z.x; rg = z.y; rb = z.z;
    } else {
      float4 nd = numden[l];
      if (nd.w != 0.f) { rr = nd.x / nd.w; rg = nd.y / nd.w; rb = nd.z / nd.w; }
      else {
        int ti = (int)(fmin[l] & 0xFFFFFFFFull);
        rr = trgb[3*ti]; rg = trgb[3*ti+1]; rb = trgb[3*ti+2];
      }
    }
    float sr = crgb[3*l]*255.f, sg = crgb[3*l+1]*255.f, sb = crgb[3*l+2]*255.f;
    loss = fabsf(sr - rr) + fabsf(sg - rg) + fabsf(sb - rb);
  }
  for (int o = 32; o > 0; o >>= 1) loss += __shfl_down(loss, o);
  if ((threadIdx.x & 63) == 0) atomicAdd(&out[1], loss);
}

extern "C" void kernel_launch(void* const* d_in, const int* in_sizes, int n_in,
                              void* d_out, int out_size, void* d_ws, size_t ws_size,
                              hipStream_t stream) {
  const float* pred = (const float*)d_in[0];
  const float* cxyz = (const float*)d_in[1];
  const float* crgb = (const float*)d_in[2];
  const float* txyz = (const float*)d_in[3];
  const float* trgb = (const float*)d_in[4];
  const int*   ktgt = (const int*)d_in[5];
  const int*   pnum = (const int*)d_in[6];
  int L = in_sizes[0];
  int N = in_sizes[3] / 3;

  // workspace layout: 16B arrays first, then 8B, 4B, bytes
  char* ws = (char*)d_ws;
  size_t off = 0;
  float4* klist  = (float4*)(ws + off);   off += (size_t)L * 16;
  float4* ttile  = (float4*)(ws + off);   off += (size_t)((N + 3) & ~3) * 16;
  float4* numden = (float4*)(ws + off);   off += (size_t)L * 16;
  float4* zcolor = (float4*)(ws + off);   off += (size_t)L * 16;
  unsigned int* key = (unsigned int*)(ws + off); off += (size_t)L * 4;  // uint4-aligned
  ull* tmin      = (ull*)(ws + off);      off += (size_t)((N + 1) & ~1) * 8;
  ull* fmin      = (ull*)(ws + off);      off += (size_t)L * 8;
  int* keep      = (int*)(ws + off);      off += (size_t)L * 4;
  int* kidx      = (int*)(ws + off);      off += (size_t)L * 4;
  int* zerohit   = (int*)(ws + off);      off += (size_t)L * 4;
  int* elist     = (int*)(ws + off);      off += (size_t)L * 4;
  float* thr_slot = (float*)(ws + off);   off += 16;
  int* counters  = (int*)(ws + off);      off += 256;   // [0]=kcount [1]=ecount
  unsigned char* islm = (unsigned char*)(ws + off); off += ((size_t)L + 15) & ~15ull;
  float* out = (float*)d_out;

  int nbL = (L + 255) / 256;   // 64
  int nbN = (N + 255) / 256;   // 40
  int mx = max(L, N);

  k_initprep<<<(mx + 255) / 256, 256, 0, stream>>>(
      pred, txyz, ttile, numden, zerohit, tmin, fmin, key, islm, counters, out, L, N);

  k_sel<<<1, 256, 0, stream>>>(key, pnum, thr_slot, L);

  k_keepc<<<nbL, 256, 0, stream>>>(
      pred, islm, thr_slot, cxyz, ktgt, keep, klist, kidx, counters, out, L);

  dim3 g2(nbN, (L + BCH - 1) / BCH);
  k_bwd<<<g2, SCAN_T, 0, stream>>>(txyz, klist, kidx, counters, tmin, N);

  k_scatter<<<nbN, 256, 0, stream>>>(trgb, tmin, numden, zerohit, zcolor, N);

  k_empty<<<nbL, 256, 0, stream>>>(keep, numden, zerohit, elist, counters, L);

  dim3 g3(nbL, (N + FCH - 1) / FCH);
  k_fwd<<<g3, SCAN_T, 0, stream>>>(ttile, cxyz, elist, counters, fmin, N);

  k_loss<<<nbL, 256, 0, stream>>>(
      crgb, trgb, keep, numden, zerohit, zcolor, fmin, out, L);
}